// Round 3
// baseline (78.496 us; speedup 1.0000x reference)
//
#include <hip/hip_runtime.h>

#define TAPS  21
#define CCH   237
#define CHUNK (TAPS * CCH)   // 4977 floats per (b,t) window, contiguous
#define NCHUNK 16384         // 32 * 512
#define NB_PAD 1248          // padded float4 count per phase table
#define TAB_OFF 32           // float offset of tables in ws (w[21] lives at 0..20)

typedef float f32x2 __attribute__((ext_vector_type(2)));
typedef float f32x4 __attribute__((ext_vector_type(4)));

// packed fp32 FMA: a += x*w (2 lanes per instruction) — hipcc never forms
// v_pk_fma_f32 from scalar fmaf, so emit it directly.
__device__ __forceinline__ void pk_fma(f32x2& a, f32x2 x, f32x2 w) {
    asm("v_pk_fma_f32 %0, %1, %2, %0" : "+v"(a) : "v"(x), "v"(w));
}

__device__ __forceinline__ void fma4pk(f32x2& al, f32x2& ah, f32x4 x, f32x4 w) {
    f32x2 xl = __builtin_shufflevector(x, x, 0, 1);
    f32x2 xh = __builtin_shufflevector(x, x, 2, 3);
    f32x2 wl = __builtin_shufflevector(w, w, 0, 1);
    f32x2 wh = __builtin_shufflevector(w, w, 2, 3);
    pk_fma(al, xl, wl);
    pk_fma(ah, xh, wh);
}

// ---------------------------------------------------------------------------
// Setup kernel: softmax weights w[21] + 4 phase-shifted expanded weight
// tables (float4-granular), ~80 KB in d_ws. Multi-block to cut latency.
// ---------------------------------------------------------------------------
__global__ void conv_weights_kernel(const float* __restrict__ p3,
                                    const float* __restrict__ p4,
                                    float* __restrict__ wsf) {
    __shared__ float w[TAPS];
    int tid = threadIdx.x;
    if (tid == 0) {
        float a = p3[0], b = p4[0];
        float lg[TAPS];
        float mx = -3.4e38f;
        for (int i = 0; i < TAPS; ++i) {
            float fi = (float)(i + 1);
            lg[i] = a * fi + b * fi * fi;
            mx = fmaxf(mx, lg[i]);
        }
        float s = 0.f;
        for (int i = 0; i < TAPS; ++i) { lg[i] = expf(lg[i] - mx); s += lg[i]; }
        float inv = 1.0f / s;
        for (int i = 0; i < TAPS; ++i) w[i] = lg[i] * inv;
    }
    __syncthreads();
    if (blockIdx.x == 0 && tid < TAPS) wsf[tid] = w[tid];
    int stride = blockDim.x * gridDim.x;
    for (int idx = blockIdx.x * blockDim.x + tid; idx < 4 * NB_PAD * 4; idx += stride) {
        int s4 = idx / (NB_PAD * 4);
        int r  = idx - s4 * (NB_PAD * 4);
        int h  = (4 - s4) & 3;
        int q  = h + r;
        wsf[TAB_OFF + idx] = (q < CHUNK) ? w[q / CCH] : 0.f;
    }
}

// ---------------------------------------------------------------------------
// Main kernel: one wave per chunk, 19 unconditional strided float4 iterations
// (4x4 + 3) + 1 predicated; inner math is 2 x v_pk_fma_f32 per float4.
// ---------------------------------------------------------------------------
__global__ __launch_bounds__(256) void conv_main_kernel(
    const float* __restrict__ in,
    const float* __restrict__ wsf,
    float* __restrict__ out) {
    int wid  = threadIdx.x >> 6;
    int lane = threadIdx.x & 63;
    int c    = (blockIdx.x << 2) + wid;          // chunk id, < 16384
    int s    = c & 3;                            // alignment phase
    int h    = (4 - s) & 3;                      // scalar prologue length
    long base = (long)c * CHUNK;
    int nb   = (CHUNK - h) >> 2;                 // float4 body count (1243/1244)
    int tail = (CHUNK - h) & 3;                  // scalar tail length

    const f32x4* in4 = (const f32x4*)(in + base + h);   // 16B aligned
    const f32x4* wt4 = (const f32x4*)(wsf + TAB_OFF + s * (NB_PAD * 4));

    f32x2 a0 = {0.f, 0.f}, a1 = a0, a2 = a0, a3 = a0;
    f32x2 a4 = a0, a5 = a0, a6 = a0, a7 = a0;

    int m = lane;
    #pragma unroll
    for (int g = 0; g < 4; ++g) {                // 16 unconditional iterations
        f32x4 x0 = in4[m      ];
        f32x4 x1 = in4[m +  64];
        f32x4 x2 = in4[m + 128];
        f32x4 x3 = in4[m + 192];
        f32x4 w0 = wt4[m      ];
        f32x4 w1 = wt4[m +  64];
        f32x4 w2 = wt4[m + 128];
        f32x4 w3 = wt4[m + 192];
        fma4pk(a0, a1, x0, w0);
        fma4pk(a2, a3, x1, w1);
        fma4pk(a4, a5, x2, w2);
        fma4pk(a6, a7, x3, w3);
        m += 256;
    }
    // 3 more unconditional (positions up to 1216+lane-1 < 1243 = min nb)
    {
        f32x4 x0 = in4[m      ];
        f32x4 x1 = in4[m +  64];
        f32x4 x2 = in4[m + 128];
        f32x4 w0 = wt4[m      ];
        f32x4 w1 = wt4[m +  64];
        f32x4 w2 = wt4[m + 128];
        fma4pk(a0, a1, x0, w0);
        fma4pk(a2, a3, x1, w1);
        fma4pk(a4, a5, x2, w2);
        m += 192;                                 // = 1216 + lane
    }
    if (m < nb) {                                 // final predicated iteration
        fma4pk(a6, a7, in4[m], wt4[m]);
    }

    float sum = ((a0.x + a0.y) + (a1.x + a1.y)) + ((a2.x + a2.y) + (a3.x + a3.y))
              + ((a4.x + a4.y) + (a5.x + a5.y)) + ((a6.x + a6.y) + (a7.x + a7.y));

    // prologue elements (tap 0) and tail elements (tap 20)
    if (lane < h)    sum += in[base + lane] * wsf[0];
    if (lane < tail) sum += in[base + h + 4 * nb + lane] * wsf[TAPS - 1];

    #pragma unroll
    for (int off = 32; off; off >>= 1) sum += __shfl_xor(sum, off, 64);

    long ob = (long)c * CCH;
    #pragma unroll
    for (int j = 0; j < 4; ++j) {
        int idx = lane + 64 * j;
        if (idx < CCH) out[ob + idx] = sum;
    }
}

// ---------------------------------------------------------------------------
// Fallback (ws too small): weights in LDS, per-element q/237 via const-div.
// ---------------------------------------------------------------------------
__global__ __launch_bounds__(256) void conv_fallback_kernel(
    const float* __restrict__ in,
    const float* __restrict__ p3,
    const float* __restrict__ p4,
    float* __restrict__ out) {
    __shared__ float w[TAPS];
    if (threadIdx.x == 0) {
        float a = p3[0], b = p4[0];
        float lg[TAPS];
        float mx = -3.4e38f;
        for (int i = 0; i < TAPS; ++i) {
            float fi = (float)(i + 1);
            lg[i] = a * fi + b * fi * fi;
            mx = fmaxf(mx, lg[i]);
        }
        float s = 0.f;
        for (int i = 0; i < TAPS; ++i) { lg[i] = expf(lg[i] - mx); s += lg[i]; }
        float inv = 1.0f / s;
        for (int i = 0; i < TAPS; ++i) w[i] = lg[i] * inv;
    }
    __syncthreads();

    int wid  = threadIdx.x >> 6;
    int lane = threadIdx.x & 63;
    int c    = (blockIdx.x << 2) + wid;
    int s    = c & 3;
    int h    = (4 - s) & 3;
    long base = (long)c * CHUNK;
    int nb   = (CHUNK - h) >> 2;
    int tail = (CHUNK - h) & 3;

    const float4* in4 = (const float4*)(in + base + h);
    float4 acc = make_float4(0.f, 0.f, 0.f, 0.f);
    for (int m = lane; m < nb; m += 64) {
        float4 x = in4[m];
        int q0 = h + 4 * m;
        acc.x = fmaf(x.x, w[(q0 + 0) / CCH], acc.x);
        acc.y = fmaf(x.y, w[(q0 + 1) / CCH], acc.y);
        acc.z = fmaf(x.z, w[(q0 + 2) / CCH], acc.z);
        acc.w = fmaf(x.w, w[(q0 + 3) / CCH], acc.w);
    }
    float sum = acc.x + acc.y + acc.z + acc.w;
    if (lane < h)    sum += in[base + lane] * w[0];
    if (lane < tail) sum += in[base + h + 4 * nb + lane] * w[TAPS - 1];

    #pragma unroll
    for (int off = 32; off; off >>= 1) sum += __shfl_xor(sum, off, 64);

    long ob = (long)c * CCH;
    for (int j = lane; j < CCH; j += 64) out[ob + j] = sum;
}

extern "C" void kernel_launch(void* const* d_in, const int* in_sizes, int n_in,
                              void* d_out, int out_size, void* d_ws, size_t ws_size,
                              hipStream_t stream) {
    const float* in = (const float*)d_in[0];
    const float* p3 = (const float*)d_in[1];
    const float* p4 = (const float*)d_in[2];
    float* out = (float*)d_out;

    size_t need = (size_t)(TAB_OFF + 4 * NB_PAD * 4) * sizeof(float);
    if (ws_size >= need && d_ws != nullptr) {
        float* wsf = (float*)d_ws;
        conv_weights_kernel<<<40, 256, 0, stream>>>(p3, p4, wsf);
        conv_main_kernel<<<NCHUNK / 4, 256, 0, stream>>>(in, wsf, out);
    } else {
        conv_fallback_kernel<<<NCHUNK / 4, 256, 0, stream>>>(in, p3, p4, out);
    }
}

// Round 4
// 64.966 us; speedup vs baseline: 1.2083x; 1.2083x over previous
//
#include <hip/hip_runtime.h>

#define TAPS  21
#define CCH   237
#define CHUNK 4977           // 21*237 floats per (b,t) window, contiguous
#define NCHUNK 16384         // 32 * 512

typedef float f32x2 __attribute__((ext_vector_type(2)));
typedef float f32x4 __attribute__((ext_vector_type(4)));

// packed fp32 FMA: a += x*w (2 lanes per instruction)
__device__ __forceinline__ void pk_fma(f32x2& a, f32x2 x, f32x2 w) {
    asm("v_pk_fma_f32 %0, %1, %2, %0" : "+v"(a) : "v"(x), "v"(w));
}

// ---------------------------------------------------------------------------
// Single kernel. One wave per chunk, 4 waves/block.
//  - wave 0 computes softmax w[21] into LDS (lane-parallel), w[21]=0 pad
//  - float4 body aligned to 64 B (prologue elems are all tap 0, tail tap 20)
//  - per-float4 tap k via magic div: k = (q*35396)>>23  (exact for q<34379)
//  - tap boundary inside a float4 (b = (k+1)*237 - q < 4) via cndmask selects
//  - 19 unconditional strided iterations (19*64=1216 <= min n4=1240) + 1 pred
// ---------------------------------------------------------------------------
__global__ __launch_bounds__(256) void conv_kernel(const float* __restrict__ in,
                                                   const float* __restrict__ p3,
                                                   const float* __restrict__ p4,
                                                   float* __restrict__ out) {
    __shared__ float w[TAPS + 1];
    int tid = threadIdx.x;
    if (tid < 32) {
        float i1 = (float)(tid + 1);
        float lg = (tid < TAPS) ? (p3[0] * i1 + p4[0] * i1 * i1) : -3.4e38f;
        float mx = lg;
        #pragma unroll
        for (int off = 16; off; off >>= 1) mx = fmaxf(mx, __shfl_xor(mx, off, 32));
        float e = (tid < TAPS) ? expf(lg - mx) : 0.f;
        float s = e;
        #pragma unroll
        for (int off = 16; off; off >>= 1) s += __shfl_xor(s, off, 32);
        if (tid < TAPS + 1) w[tid] = e / s;      // tid==21 -> 0 (pad)
    }
    __syncthreads();

    int wid  = tid >> 6;
    int lane = tid & 63;
    int c    = (blockIdx.x << 2) + wid;          // chunk id, < 16384
    long base = (long)c * CHUNK;
    int h    = (16 - (c & 15)) & 15;             // floats to 64B boundary (<=15, all tap 0)
    int n4   = (CHUNK - h) >> 2;                 // 1240..1244
    int tail = (CHUNK - h) & 3;                  // <=3, all tap 20

    const f32x4* in4 = (const f32x4*)(in + base + h);   // 64B aligned
    int q0 = h + (lane << 2);

    f32x2 acc[8];
    #pragma unroll
    for (int i = 0; i < 8; ++i) acc[i] = (f32x2){0.f, 0.f};

    #pragma unroll
    for (int it = 0; it < 19; ++it) {            // fully unrolled, indices static
        f32x4 x = in4[lane + (it << 6)];
        int q = q0 + (it << 8);
        int k = (q * 35396) >> 23;               // q/237
        float wk = w[k], wk1 = w[k + 1];
        int b = k * CCH + CCH - q;               // elems e >= b belong to tap k+1
        f32x2 wlo = { wk,               (1 < b) ? wk : wk1 };
        f32x2 whi = { (2 < b) ? wk : wk1, (3 < b) ? wk : wk1 };
        f32x2 xlo = __builtin_shufflevector(x, x, 0, 1);
        f32x2 xhi = __builtin_shufflevector(x, x, 2, 3);
        pk_fma(acc[(2 * it) & 7], xlo, wlo);
        pk_fma(acc[(2 * it + 1) & 7], xhi, whi);
    }
    {   // final predicated iteration (m in [1216, n4))
        int m = 1216 + lane;
        if (m < n4) {
            f32x4 x = in4[m];
            int q = h + (m << 2);
            int k = (q * 35396) >> 23;
            float wk = w[k], wk1 = w[k + 1];
            int b = k * CCH + CCH - q;
            f32x2 wlo = { wk,               (1 < b) ? wk : wk1 };
            f32x2 whi = { (2 < b) ? wk : wk1, (3 < b) ? wk : wk1 };
            f32x2 xlo = __builtin_shufflevector(x, x, 0, 1);
            f32x2 xhi = __builtin_shufflevector(x, x, 2, 3);
            pk_fma(acc[6], xlo, wlo);
            pk_fma(acc[7], xhi, whi);
        }
    }

    float sum = ((acc[0].x + acc[0].y) + (acc[1].x + acc[1].y))
              + ((acc[2].x + acc[2].y) + (acc[3].x + acc[3].y))
              + ((acc[4].x + acc[4].y) + (acc[5].x + acc[5].y))
              + ((acc[6].x + acc[6].y) + (acc[7].x + acc[7].y));

    // prologue (tap 0) and tail (tap 20) scalars
    if (lane < h)    sum += in[base + lane] * w[0];
    if (lane < tail) sum += in[base + h + 4 * (long)n4 + lane] * w[TAPS - 1];

    #pragma unroll
    for (int off = 32; off; off >>= 1) sum += __shfl_xor(sum, off, 64);

    long ob = (long)c * CCH;
    #pragma unroll
    for (int j = 0; j < 4; ++j) {
        int idx = lane + 64 * j;
        if (idx < CCH) out[ob + idx] = sum;
    }
}

extern "C" void kernel_launch(void* const* d_in, const int* in_sizes, int n_in,
                              void* d_out, int out_size, void* d_ws, size_t ws_size,
                              hipStream_t stream) {
    const float* in = (const float*)d_in[0];
    const float* p3 = (const float*)d_in[1];
    const float* p4 = (const float*)d_in[2];
    float* out = (float*)d_out;
    conv_kernel<<<NCHUNK / 4, 256, 0, stream>>>(in, p3, p4, out);
}

// Round 5
// 59.529 us; speedup vs baseline: 1.3186x; 1.0913x over previous
//
#include <hip/hip_runtime.h>

#define TAPS  21
#define CCH   237
#define CHUNK 4977           // 21*237 floats per (b,t) window, contiguous
#define NCHUNK 16384         // 32 * 512

typedef float f32x2 __attribute__((ext_vector_type(2)));
typedef float f32x4 __attribute__((ext_vector_type(4)));

// packed fp32 FMA: a += x*w (2 lanes per instruction)
__device__ __forceinline__ void pk_fma(f32x2& a, f32x2 x, f32x2 w) {
    asm("v_pk_fma_f32 %0, %1, %2, %0" : "+v"(a) : "v"(x), "v"(w));
}

// ---------------------------------------------------------------------------
// Single kernel. One wave per chunk, 4 waves/block.
//  - wave 0 computes softmax w[21] into LDS (lane-parallel), w[21]=0 pad
//  - float4 body aligned to 64 B (prologue elems are all tap 0, tail tap 20)
//  - per-float4 tap k via magic div: k = (q*35396)>>23  (exact for q<34379)
//  - tap boundary inside a float4 (b = (k+1)*237 - q < 4) via cndmask selects
//  - 19 unconditional strided iterations (19*64=1216 <= min n4=1240) + 1 pred
//  - NEW: non-temporal (evict-first) loads for the read-once input stream and
//    non-temporal stores for the output, to stop thrashing L2.
// ---------------------------------------------------------------------------
__global__ __launch_bounds__(256) void conv_kernel(const float* __restrict__ in,
                                                   const float* __restrict__ p3,
                                                   const float* __restrict__ p4,
                                                   float* __restrict__ out) {
    __shared__ float w[TAPS + 1];
    int tid = threadIdx.x;
    if (tid < 32) {
        float i1 = (float)(tid + 1);
        float lg = (tid < TAPS) ? (p3[0] * i1 + p4[0] * i1 * i1) : -3.4e38f;
        float mx = lg;
        #pragma unroll
        for (int off = 16; off; off >>= 1) mx = fmaxf(mx, __shfl_xor(mx, off, 32));
        float e = (tid < TAPS) ? expf(lg - mx) : 0.f;
        float s = e;
        #pragma unroll
        for (int off = 16; off; off >>= 1) s += __shfl_xor(s, off, 32);
        if (tid < TAPS + 1) w[tid] = e / s;      // tid==21 -> 0 (pad)
    }
    __syncthreads();

    int wid  = tid >> 6;
    int lane = tid & 63;
    int c    = (blockIdx.x << 2) + wid;          // chunk id, < 16384
    long base = (long)c * CHUNK;
    int h    = (16 - (c & 15)) & 15;             // floats to 64B boundary (<=15, all tap 0)
    int n4   = (CHUNK - h) >> 2;                 // 1240..1244
    int tail = (CHUNK - h) & 3;                  // <=3, all tap 20

    const f32x4* in4 = (const f32x4*)(in + base + h);   // 64B aligned
    int q0 = h + (lane << 2);

    f32x2 acc[8];
    #pragma unroll
    for (int i = 0; i < 8; ++i) acc[i] = (f32x2){0.f, 0.f};

    #pragma unroll
    for (int it = 0; it < 19; ++it) {            // fully unrolled, indices static
        f32x4 x = __builtin_nontemporal_load(&in4[lane + (it << 6)]);
        int q = q0 + (it << 8);
        int k = (q * 35396) >> 23;               // q/237
        float wk = w[k], wk1 = w[k + 1];
        int b = k * CCH + CCH - q;               // elems e >= b belong to tap k+1
        f32x2 wlo = { wk,               (1 < b) ? wk : wk1 };
        f32x2 whi = { (2 < b) ? wk : wk1, (3 < b) ? wk : wk1 };
        f32x2 xlo = __builtin_shufflevector(x, x, 0, 1);
        f32x2 xhi = __builtin_shufflevector(x, x, 2, 3);
        pk_fma(acc[(2 * it) & 7], xlo, wlo);
        pk_fma(acc[(2 * it + 1) & 7], xhi, whi);
    }
    {   // final predicated iteration (m in [1216, n4))
        int m = 1216 + lane;
        if (m < n4) {
            f32x4 x = __builtin_nontemporal_load(&in4[m]);
            int q = h + (m << 2);
            int k = (q * 35396) >> 23;
            float wk = w[k], wk1 = w[k + 1];
            int b = k * CCH + CCH - q;
            f32x2 wlo = { wk,               (1 < b) ? wk : wk1 };
            f32x2 whi = { (2 < b) ? wk : wk1, (3 < b) ? wk : wk1 };
            f32x2 xlo = __builtin_shufflevector(x, x, 0, 1);
            f32x2 xhi = __builtin_shufflevector(x, x, 2, 3);
            pk_fma(acc[6], xlo, wlo);
            pk_fma(acc[7], xhi, whi);
        }
    }

    float sum = ((acc[0].x + acc[0].y) + (acc[1].x + acc[1].y))
              + ((acc[2].x + acc[2].y) + (acc[3].x + acc[3].y))
              + ((acc[4].x + acc[4].y) + (acc[5].x + acc[5].y))
              + ((acc[6].x + acc[6].y) + (acc[7].x + acc[7].y));

    // prologue (tap 0) and tail (tap 20) scalars
    if (lane < h)    sum += in[base + lane] * w[0];
    if (lane < tail) sum += in[base + h + 4 * (long)n4 + lane] * w[TAPS - 1];

    #pragma unroll
    for (int off = 32; off; off >>= 1) sum += __shfl_xor(sum, off, 64);

    long ob = (long)c * CCH;
    #pragma unroll
    for (int j = 0; j < 4; ++j) {
        int idx = lane + 64 * j;
        if (idx < CCH) __builtin_nontemporal_store(sum, &out[ob + idx]);
    }
}

extern "C" void kernel_launch(void* const* d_in, const int* in_sizes, int n_in,
                              void* d_out, int out_size, void* d_ws, size_t ws_size,
                              hipStream_t stream) {
    const float* in = (const float*)d_in[0];
    const float* p3 = (const float*)d_in[1];
    const float* p4 = (const float*)d_in[2];
    float* out = (float*)d_out;
    conv_kernel<<<NCHUNK / 4, 256, 0, stream>>>(in, p3, p4, out);
}